// Round 5
// baseline (319.917 us; speedup 1.0000x reference)
//
#include <hip/hip_runtime.h>
#include <hip/hip_bf16.h>
#include <stdint.h>

#define M_DIM 8192   // B*S
#define K_DIM 4096   // IN
#define N_DIM 4096   // OUT
#define NPIECE (K_DIM / 32)   // 128 K-pieces of 32

typedef __bf16 bf16x8v __attribute__((ext_vector_type(8)));
typedef float f32x4 __attribute__((ext_vector_type(4)));

__device__ __forceinline__ unsigned short f2bf(float f) {
    unsigned int u = __builtin_bit_cast(unsigned int, f);
    u += 0x7FFFu + ((u >> 16) & 1u);   // round-to-nearest-even
    return (unsigned short)(u >> 16);
}

__device__ __forceinline__ void bar() {
    asm volatile("" ::: "memory");
    __builtin_amdgcn_s_barrier();
    asm volatile("" ::: "memory");
}

// ---------- dequant: qweight [N][K/2] int32 (one packed byte each) -> W bf16 [N][K]
__global__ void k_dequant(const int4* __restrict__ qw4,
                          const float* __restrict__ scales,
                          const float* __restrict__ lut,
                          uint4* __restrict__ wb4) {
    __shared__ float sl[16];
    if (threadIdx.x < 16) sl[threadIdx.x] = lut[threadIdx.x];
    __syncthreads();
    int t = blockIdx.x * blockDim.x + threadIdx.x;   // exactly N*(K/2)/4 threads
    int4 q = qw4[t];
    int o = t >> 9;                   // row (512 int4 per row)
    int col0 = (t & 511) << 3;        // first of 8 output cols
    float s = scales[(o << 5) + (col0 >> 7)];   // GS=128
    int v[4] = {q.x, q.y, q.z, q.w};
    unsigned int pk[4];
#pragma unroll
    for (int j = 0; j < 4; ++j) {
        float w0 = sl[v[j] & 15] * s;          // low nibble first
        float w1 = sl[(v[j] >> 4) & 15] * s;
        pk[j] = (unsigned int)f2bf(w0) | ((unsigned int)f2bf(w1) << 16);
    }
    uint4 r; r.x = pk[0]; r.y = pk[1]; r.z = pk[2]; r.w = pk[3];
    wb4[t] = r;
}

// ---------- x f32 -> bf16
__global__ void k_cvt(const float4* __restrict__ x4, uint4* __restrict__ xb4) {
    int t = blockIdx.x * blockDim.x + threadIdx.x;   // exactly M*K/8 threads
    float4 a = x4[2 * t], b = x4[2 * t + 1];
    uint4 o;
    o.x = (unsigned int)f2bf(a.x) | ((unsigned int)f2bf(a.y) << 16);
    o.y = (unsigned int)f2bf(a.z) | ((unsigned int)f2bf(a.w) << 16);
    o.z = (unsigned int)f2bf(b.x) | ((unsigned int)f2bf(b.y) << 16);
    o.w = (unsigned int)f2bf(b.z) | ((unsigned int)f2bf(b.w) << 16);
    xb4[t] = o;
}

#define GLL16(SRC, DST)                                                              \
    __builtin_amdgcn_global_load_lds((__attribute__((address_space(1))) void*)(SRC), \
                                     (__attribute__((address_space(3))) void*)(DST), \
                                     16, 0, 0)

// ---------- GEMM: C[M][N] = Xb[M][K] * Wb[N][K]^T + bias
// 256x128 tile, 8 waves (4Mx2N), 64x64 per wave, K in 32-wide pieces,
// 2 LDS slots x 24KB (48KB total -> 2 blocks/CU, 4 independent waves/SIMD),
// reg budget <=128 (launch_bounds 512,4), XOR-swizzled LDS, counted staging.
__global__ __launch_bounds__(512, 4) void k_gemm(const __hip_bfloat16* __restrict__ A,
                                                 const __hip_bfloat16* __restrict__ Bw,
                                                 const float* __restrict__ bias,
                                                 float* __restrict__ C) {
    // slot: A piece [256 rows][32 K] bf16 (16KB) then B piece [128 rows][32 K] (8KB)
    __shared__ __align__(16) char lds[2][24576];   // 48 KiB

    const int tid  = threadIdx.x;
    const int lane = tid & 63;
    const int wave = tid >> 6;
    const int wm = wave >> 1;      // 0..3 -> M quarter (64 rows)
    const int wn = wave & 1;       // 0..1 -> N half (64 cols)

    // bijective XCD swizzle: nwg=1024, 128 contiguous wgids per XCD
    const int swz = (blockIdx.x & 7) * 128 + (blockIdx.x >> 3);
    const int bm = swz >> 5;       // 0..31 (M/256)
    const int bn = swz & 31;       // 0..31 (N/128)

    f32x4 acc[4][4];
    const f32x4 z = {0.f, 0.f, 0.f, 0.f};
#pragma unroll
    for (int i = 0; i < 4; ++i)
#pragma unroll
        for (int j = 0; j < 4; ++j) acc[i][j] = z;

    // ---- staging addresses (pre-swizzled per-lane global source, linear LDS dest)
    // each gll issue covers 8KB = 128 rows x 64B: thread t -> row t>>2, granule t&3
    const int lrow = tid >> 2;                 // 0..127
    const int sg   = (tid & 3) ^ ((lrow >> 1) & 3);   // swizzled source granule
    const char* aSrc = (const char*)A  + ((size_t)(bm * 256 + lrow) * K_DIM) * 2 + sg * 16;
    const char* bSrc = (const char*)Bw + ((size_t)(bn * 128 + lrow) * K_DIM) * 2 + sg * 16;
    const size_t hop = (size_t)128 * K_DIM * 2;   // +128 rows (A second issue)
    const int woff = wave * 1024;                 // wave-uniform LDS dest base offset

    // ---- ds_read addresses (swizzled)
    const int r   = lane & 15;
    const int kq  = lane >> 4;                  // K granule wanted
    const int gsw = kq ^ ((r >> 1) & 3);        // swizzled granule
    const int aOff = (wm * 64 + r) * 64 + gsw * 16;            // + m*1024
    const int bOff = 16384 + (wn * 64 + r) * 64 + gsw * 16;    // + n*1024
    const char* ldsb = (const char*)&lds[0][0];
    char* ldsw = (char*)&lds[0][0];

#define STAGE_A(P)                                                           \
    do {                                                                     \
        char* d_ = ldsw + ((P) & 1) * 24576;                                 \
        const size_t ko_ = (size_t)(P) * 64;                                 \
        GLL16(aSrc + ko_,       d_ + 0    + woff);                           \
        GLL16(aSrc + hop + ko_, d_ + 8192 + woff);                           \
    } while (0)
#define STAGE_B(P)                                                           \
    do {                                                                     \
        char* d_ = ldsw + ((P) & 1) * 24576 + 16384;                         \
        const size_t ko_ = (size_t)(P) * 64;                                 \
        GLL16(bSrc + ko_, d_ + woff);                                        \
    } while (0)

    // ---- prologue: stage pieces 0 and 1 (6 loads); piece-1's 3 stay in flight
    STAGE_A(0); STAGE_B(0);
    STAGE_A(1); STAGE_B(1);
    asm volatile("s_waitcnt vmcnt(3)" ::: "memory");
    bar();

    // ---- main loop: reads -> MFMA -> vmcnt(0)+bar -> stage(p+2)
    for (int p = 0; p < NPIECE; ++p) {
        const char* sl = ldsb + (p & 1) * 24576;
        bf16x8v aF[4], bF[4];
#pragma unroll
        for (int m = 0; m < 4; ++m)
            aF[m] = *(const bf16x8v*)(sl + aOff + m * 1024);
#pragma unroll
        for (int n = 0; n < 4; ++n)
            bF[n] = *(const bf16x8v*)(sl + bOff + n * 1024);
        __builtin_amdgcn_s_setprio(1);
#pragma unroll
        for (int m = 0; m < 4; ++m)
#pragma unroll
            for (int n = 0; n < 4; ++n)
                acc[m][n] = __builtin_amdgcn_mfma_f32_16x16x32_bf16(aF[m], bF[n], acc[m][n], 0, 0, 0);
        __builtin_amdgcn_s_setprio(0);
        asm volatile("s_waitcnt vmcnt(0)" ::: "memory");   // stage(p+1) landed (issued last piece)
        bar();
        if (p + 2 < NPIECE) { STAGE_A(p + 2); STAGE_B(p + 2); }
    }

#undef STAGE_A
#undef STAGE_B

    // ---- epilogue: C/D layout col=lane&15, row=(lane>>4)*4+j
    const int q   = lane >> 4;
    const int gr0 = bm * 256 + wm * 64;
    const int gc0 = bn * 128 + wn * 64 + r;
    float bv[4];
#pragma unroll
    for (int n = 0; n < 4; ++n) bv[n] = bias[gc0 + n * 16];
#pragma unroll
    for (int m = 0; m < 4; ++m)
#pragma unroll
        for (int j = 0; j < 4; ++j) {
            float* crow = C + (size_t)(gr0 + m * 16 + q * 4 + j) * N_DIM + gc0;
#pragma unroll
            for (int n = 0; n < 4; ++n)
                crow[n * 16] = acc[m][n][j] + bv[n];
        }
}

// ---------- naive fallback (only if ws too small)
__global__ void k_naive(const float* __restrict__ x, const int* __restrict__ qw,
                        const float* __restrict__ scales, const float* __restrict__ bias,
                        const float* __restrict__ lut, float* __restrict__ y) {
    long t = (long)blockIdx.x * blockDim.x + threadIdx.x;
    if (t >= (long)M_DIM * N_DIM) return;
    int m = (int)(t / N_DIM), n = (int)(t % N_DIM);
    float acc = 0.f;
    for (int k = 0; k < K_DIM; k += 2) {
        int b = qw[n * (K_DIM / 2) + (k >> 1)];
        float s = scales[n * 32 + (k >> 7)];
        acc += x[(size_t)m * K_DIM + k]     * lut[b & 15]        * s;
        acc += x[(size_t)m * K_DIM + k + 1] * lut[(b >> 4) & 15] * s;
    }
    y[t] = acc + bias[n];
}

extern "C" void kernel_launch(void* const* d_in, const int* in_sizes, int n_in,
                              void* d_out, int out_size, void* d_ws, size_t ws_size,
                              hipStream_t stream) {
    const float* x      = (const float*)d_in[0];
    const int*   qw     = (const int*)d_in[1];
    const float* scales = (const float*)d_in[2];
    const float* bias   = (const float*)d_in[3];
    const float* lut    = (const float*)d_in[5];
    float* y = (float*)d_out;

    const size_t wbBytes = (size_t)N_DIM * K_DIM * 2;   // 32 MiB
    const size_t xbBytes = (size_t)M_DIM * K_DIM * 2;   // 64 MiB
    if (ws_size < wbBytes + xbBytes) {
        long total = (long)M_DIM * N_DIM;
        k_naive<<<(int)((total + 255) / 256), 256, 0, stream>>>(x, qw, scales, bias, lut, y);
        return;
    }
    __hip_bfloat16* Wb = (__hip_bfloat16*)d_ws;
    __hip_bfloat16* Xb = (__hip_bfloat16*)((char*)d_ws + wbBytes);

    k_dequant<<<N_DIM * (K_DIM / 2) / 4 / 256, 256, 0, stream>>>(
        (const int4*)qw, scales, lut, (uint4*)Wb);
    k_cvt<<<(int)((size_t)M_DIM * K_DIM / 8 / 256), 256, 0, stream>>>(
        (const float4*)x, (uint4*)Xb);
    k_gemm<<<1024, 512, 0, stream>>>(Xb, Wb, bias, y);
}

// Round 7
// 279.869 us; speedup vs baseline: 1.1431x; 1.1431x over previous
//
#include <hip/hip_runtime.h>
#include <hip/hip_bf16.h>
#include <stdint.h>

#define M_DIM 8192   // B*S
#define K_DIM 4096   // IN
#define N_DIM 4096   // OUT

typedef __bf16 bf16x8v __attribute__((ext_vector_type(8)));
typedef float f32x4 __attribute__((ext_vector_type(4)));

__device__ __forceinline__ unsigned short f2bf(float f) {
    unsigned int u = __builtin_bit_cast(unsigned int, f);
    u += 0x7FFFu + ((u >> 16) & 1u);   // round-to-nearest-even
    return (unsigned short)(u >> 16);
}

// ---------- dequant: qweight [N][K/2] int32 (one packed byte each) -> W bf16 [N][K]
__global__ void k_dequant(const int4* __restrict__ qw4,
                          const float* __restrict__ scales,
                          const float* __restrict__ lut,
                          uint4* __restrict__ wb4) {
    __shared__ float sl[16];
    if (threadIdx.x < 16) sl[threadIdx.x] = lut[threadIdx.x];
    __syncthreads();
    int t = blockIdx.x * blockDim.x + threadIdx.x;   // exactly N*(K/2)/4 threads
    int4 q = qw4[t];
    int o = t >> 9;                   // row (512 int4 per row)
    int col0 = (t & 511) << 3;        // first of 8 output cols
    float s = scales[(o << 5) + (col0 >> 7)];   // GS=128
    int v[4] = {q.x, q.y, q.z, q.w};
    unsigned int pk[4];
#pragma unroll
    for (int j = 0; j < 4; ++j) {
        float w0 = sl[v[j] & 15] * s;          // low nibble first
        float w1 = sl[(v[j] >> 4) & 15] * s;
        pk[j] = (unsigned int)f2bf(w0) | ((unsigned int)f2bf(w1) << 16);
    }
    uint4 rr; rr.x = pk[0]; rr.y = pk[1]; rr.z = pk[2]; rr.w = pk[3];
    wb4[t] = rr;
}

// ---------- x f32 -> bf16
__global__ void k_cvt(const float4* __restrict__ x4, uint4* __restrict__ xb4) {
    int t = blockIdx.x * blockDim.x + threadIdx.x;   // exactly M*K/8 threads
    float4 a = x4[2 * t], b = x4[2 * t + 1];
    uint4 o;
    o.x = (unsigned int)f2bf(a.x) | ((unsigned int)f2bf(a.y) << 16);
    o.y = (unsigned int)f2bf(a.z) | ((unsigned int)f2bf(a.w) << 16);
    o.z = (unsigned int)f2bf(b.x) | ((unsigned int)f2bf(b.y) << 16);
    o.w = (unsigned int)f2bf(b.z) | ((unsigned int)f2bf(b.w) << 16);
    xb4[t] = o;
}

#define GLL16(SRC, DST)                                                              \
    __builtin_amdgcn_global_load_lds((__attribute__((address_space(1))) void*)(SRC), \
                                     (__attribute__((address_space(3))) void*)(DST), \
                                     16, 0, 0)

// ---------- GEMM: C[M][N] = Xb[M][K] * Wb[N][K]^T + bias
// 8-phase template: 256x256 tile, BK=64, 8 waves (2Mx4N, 128x64/wave),
// 2 LDS buffers (A 32KB + B 32KB each), XOR swizzle granule^=(row&7).
// RACE-FREE stage schedule: A(kt+1) -> idle buffer at P0; B(kt+2) -> current
// buffer's B slots at P1 (B fully read at P0, barrier-ordered). vmcnt(4)
// once per K-tile, vmcnt(0) only in the tail.
__global__ __launch_bounds__(512, 2) void k_gemm(const __hip_bfloat16* __restrict__ A,
                                                 const __hip_bfloat16* __restrict__ Bw,
                                                 const float* __restrict__ bias,
                                                 float* __restrict__ C) {
    // buffer b at b*65536: A rows 0..255 (row*128B) at +0, B rows 0..255 at +32768.
    // slot s (0..7): buffer s>>2, part s&3 in {A-lo, A-hi, B-lo, B-hi} (16KB each)
    __shared__ __align__(16) char lds[2][65536];   // 128 KiB

    const int tid  = threadIdx.x;
    const int lane = tid & 63;
    const int wave = tid >> 6;
    const int wm = wave >> 2;      // 0..1 -> M half (128 rows)
    const int wn = wave & 3;       // 0..3 -> N quarter (64 cols)
    const int bm = blockIdx.y, bn = blockIdx.x;

    f32x4 acc[8][4];
    const f32x4 z = {0.f, 0.f, 0.f, 0.f};
#pragma unroll
    for (int i = 0; i < 8; ++i)
#pragma unroll
        for (int j = 0; j < 4; ++j) acc[i][j] = z;

    // ---- staging: one half-tile = 128 rows x 128B = 16KB = 2 gll issues of 8KB.
    // thread t -> LDS row t>>3 (+64 for issue 1), LDS granule t&7 (16B each).
    // source pre-swizzled: src granule = (t&7) ^ (row&7); LDS dest linear.
    const int srow = tid >> 3;                    // 0..63
    const int sg   = (tid & 7) ^ (srow & 7);      // swizzled source granule
    const char* aStage = (const char*)A  + ((size_t)(bm * 256 + srow) * K_DIM) * 2 + sg * 16;
    const char* bStage = (const char*)Bw + ((size_t)(bn * 256 + srow) * K_DIM) * 2 + sg * 16;
    const int woff = wave * 1024;                 // wave-uniform dest offset within 8KB chunk
    char* ldsw = &lds[0][0];
    const char* ldsb = &lds[0][0];

    // ---- ds_read: lane (r,kq); row = 8 granules of 16B; global granule G read at
    // LDS granule G^(row&7); frag granules kq (ks=0) and kq+4 (ks=1)
    const int r  = lane & 15;
    const int kq = lane >> 4;
    const int g0 = ((kq)     ^ (r & 7)) * 16;
    const int g1 = ((kq + 4) ^ (r & 7)) * 16;
    const int aRd = (wm * 128 + r) * 128;         // + mi*2048 + g{0,1}
    const int bRd = 32768 + (wn * 64 + r) * 128;  // + ni*2048 + g{0,1}

    bf16x8v aQ[2][2], bQ[4][2];

#define LDSOFF(S) (((S) >> 2) * 65536 + ((S) & 3) * 16384)
    // stage half-tile into slot S. ISB: 0=A,1=B; HALF: 0=rows0-127,1=rows128-255; KT: K-tile
#define STAGE_HT(S, ISB, HALF, KT)                                                          \
    do {                                                                                    \
        char* d_ = ldsw + LDSOFF(S) + woff;                                                 \
        const char* s_ = ((ISB) ? bStage : aStage) + (size_t)(HALF) * 128 * K_DIM * 2       \
                         + (size_t)(KT) * 128;                                              \
        GLL16(s_, d_);                                                                      \
        GLL16(s_ + (size_t)64 * K_DIM * 2, d_ + 8192);                                      \
    } while (0)

    // one phase: ds-reads (A quad P; +all B on P==0), stage (DOA at P0: A(kt+1) into
    // idle buffer; DOB at P1: B(kt+2) into current buffer's B slots), barrier,
    // lgkmcnt(0), 16 MFMA, [vmcnt], barrier.
#define PHASE(BUF, P, KTV, DOA, DOB, WAITN)                                                 \
    do {                                                                                    \
        const char* sb_ = ldsb + (BUF) * 65536;                                             \
        _Pragma("unroll") for (int j = 0; j < 2; ++j) {                                     \
            aQ[j][0] = *(const bf16x8v*)(sb_ + aRd + (2 * (P) + j) * 2048 + g0);            \
            aQ[j][1] = *(const bf16x8v*)(sb_ + aRd + (2 * (P) + j) * 2048 + g1);            \
        }                                                                                   \
        if ((P) == 0) {                                                                     \
            _Pragma("unroll") for (int n = 0; n < 4; ++n) {                                 \
                bQ[n][0] = *(const bf16x8v*)(sb_ + bRd + n * 2048 + g0);                    \
                bQ[n][1] = *(const bf16x8v*)(sb_ + bRd + n * 2048 + g1);                    \
            }                                                                               \
        }                                                                                   \
        if ((P) == 0 && (DOA)) {                                                            \
            STAGE_HT((BUF) ? 0 : 4, 0, 0, (KTV) + 1);                                       \
            STAGE_HT((BUF) ? 1 : 5, 0, 1, (KTV) + 1);                                       \
        }                                                                                   \
        if ((P) == 1 && (DOB)) {                                                            \
            STAGE_HT((BUF) ? 6 : 2, 1, 0, (KTV) + 2);                                       \
            STAGE_HT((BUF) ? 7 : 3, 1, 1, (KTV) + 2);                                       \
        }                                                                                   \
        if ((P) == 0) asm volatile("s_waitcnt lgkmcnt(8)" ::: "memory");                    \
        asm volatile("" ::: "memory");                                                      \
        __builtin_amdgcn_s_barrier();                                                       \
        asm volatile("s_waitcnt lgkmcnt(0)" ::: "memory");                                  \
        __builtin_amdgcn_s_setprio(1);                                                      \
        _Pragma("unroll") for (int j = 0; j < 2; ++j)                                       \
            _Pragma("unroll") for (int ks = 0; ks < 2; ++ks)                                 \
                _Pragma("unroll") for (int n = 0; n < 4; ++n)                                \
                    acc[2 * (P) + j][n] = __builtin_amdgcn_mfma_f32_16x16x32_bf16(           \
                        aQ[j][ks], bQ[n][ks], acc[2 * (P) + j][n], 0, 0, 0);                 \
        __builtin_amdgcn_s_setprio(0);                                                      \
        if ((WAITN) == 4) asm volatile("s_waitcnt vmcnt(4)" ::: "memory");                  \
        if ((WAITN) == 0) asm volatile("s_waitcnt vmcnt(0)" ::: "memory");                  \
        asm volatile("" ::: "memory");                                                      \
        __builtin_amdgcn_s_barrier();                                                       \
        asm volatile("" ::: "memory");                                                      \
    } while (0)

    // ---- prologue: B(0), A(0), B(1) in issue order (12 loads); drain to B(1) in flight
    STAGE_HT(2, 1, 0, 0); STAGE_HT(3, 1, 1, 0);   // B(0) -> buf0
    STAGE_HT(0, 0, 0, 0); STAGE_HT(1, 0, 1, 0);   // A(0) -> buf0
    STAGE_HT(6, 1, 0, 1); STAGE_HT(7, 1, 1, 1);   // B(1) -> buf1
    asm volatile("s_waitcnt vmcnt(4)" ::: "memory");   // B(0), A(0) landed
    asm volatile("" ::: "memory");
    __builtin_amdgcn_s_barrier();
    asm volatile("" ::: "memory");

    // ---- main loop: kt = 0..61
    for (int kt2 = 0; kt2 < 62; kt2 += 2) {
        PHASE(0, 0, kt2, 1, 0, -1);
        PHASE(0, 1, kt2, 0, 1, -1);
        PHASE(0, 2, kt2, 0, 0, -1);
        PHASE(0, 3, kt2, 0, 0, 4);
        PHASE(1, 0, kt2 + 1, 1, 0, -1);
        PHASE(1, 1, kt2 + 1, 0, 1, -1);
        PHASE(1, 2, kt2 + 1, 0, 0, -1);
        PHASE(1, 3, kt2 + 1, 0, 0, 4);
    }
    // ---- tail: kt62 stages A(63) only then full drain; kt63 stages nothing
    PHASE(0, 0, 62, 1, 0, -1);
    PHASE(0, 1, 62, 0, 0, -1);
    PHASE(0, 2, 62, 0, 0, -1);
    PHASE(0, 3, 62, 0, 0, 0);
    PHASE(1, 0, 63, 0, 0, -1);
    PHASE(1, 1, 63, 0, 0, -1);
    PHASE(1, 2, 63, 0, 0, -1);
    PHASE(1, 3, 63, 0, 0, -1);

#undef PHASE
#undef STAGE_HT
#undef LDSOFF

    // ---- epilogue: C/D layout col=lane&15, row=(lane>>4)*4+j
    const int q   = lane >> 4;
    const int gr0 = bm * 256 + wm * 128;
    const int gc0 = bn * 256 + wn * 64 + r;
    float bv[4];
#pragma unroll
    for (int n = 0; n < 4; ++n) bv[n] = bias[gc0 + n * 16];
#pragma unroll
    for (int m = 0; m < 8; ++m)
#pragma unroll
        for (int j = 0; j < 4; ++j) {
            float* crow = C + (size_t)(gr0 + m * 16 + q * 4 + j) * N_DIM + gc0;
#pragma unroll
            for (int n = 0; n < 4; ++n)
                crow[n * 16] = acc[m][n][j] + bv[n];
        }
}

// ---------- naive fallback (only if ws too small)
__global__ void k_naive(const float* __restrict__ x, const int* __restrict__ qw,
                        const float* __restrict__ scales, const float* __restrict__ bias,
                        const float* __restrict__ lut, float* __restrict__ y) {
    long t = (long)blockIdx.x * blockDim.x + threadIdx.x;
    if (t >= (long)M_DIM * N_DIM) return;
    int m = (int)(t / N_DIM), n = (int)(t % N_DIM);
    float acc = 0.f;
    for (int k = 0; k < K_DIM; k += 2) {
        int b = qw[n * (K_DIM / 2) + (k >> 1)];
        float s = scales[n * 32 + (k >> 7)];
        acc += x[(size_t)m * K_DIM + k]     * lut[b & 15]        * s;
        acc += x[(size_t)m * K_DIM + k + 1] * lut[(b >> 4) & 15] * s;
    }
    y[t] = acc + bias[n];
}

extern "C" void kernel_launch(void* const* d_in, const int* in_sizes, int n_in,
                              void* d_out, int out_size, void* d_ws, size_t ws_size,
                              hipStream_t stream) {
    const float* x      = (const float*)d_in[0];
    const int*   qw     = (const int*)d_in[1];
    const float* scales = (const float*)d_in[2];
    const float* bias   = (const float*)d_in[3];
    const float* lut    = (const float*)d_in[5];
    float* y = (float*)d_out;

    const size_t wbBytes = (size_t)N_DIM * K_DIM * 2;   // 32 MiB
    const size_t xbBytes = (size_t)M_DIM * K_DIM * 2;   // 64 MiB
    if (ws_size < wbBytes + xbBytes) {
        long total = (long)M_DIM * N_DIM;
        k_naive<<<(int)((total + 255) / 256), 256, 0, stream>>>(x, qw, scales, bias, lut, y);
        return;
    }
    __hip_bfloat16* Wb = (__hip_bfloat16*)d_ws;
    __hip_bfloat16* Xb = (__hip_bfloat16*)((char*)d_ws + wbBytes);

    k_dequant<<<N_DIM * (K_DIM / 2) / 4 / 256, 256, 0, stream>>>(
        (const int4*)qw, scales, lut, (uint4*)Wb);
    k_cvt<<<(int)((size_t)M_DIM * K_DIM / 8 / 256), 256, 0, stream>>>(
        (const float4*)x, (uint4*)Xb);
    dim3 grid(N_DIM / 256, M_DIM / 256);
    k_gemm<<<grid, 512, 0, stream>>>(Xb, Wb, bias, y);
}